// Round 13
// baseline (1690.728 us; speedup 1.0000x reference)
//
#include <hip/hip_runtime.h>
#include <math.h>

// DGM edge sampler, N=8192, DIN=512, DEMB=256, K=16.
// Canonical-f32 pipeline for h and all REFINED scores (bit-faithful to the
// np reference). bf16 MFMA screening + exact f32 refine for the O(N^2) part.
// Round 13: k_tile rebuilt for co-residency: 256 thr, 32x256 tile, 8x4/thread,
// BK=16 -> 36KB LDS -> 3-4 blocks/CU (was 72KB, 1 block/CU, 52% stall).
// k-order unchanged (0..KTOT-1 ascending) -> bit-identical h.

#define NN 8192
#define DI 512
#define DE 256
#define TK 16

typedef float4 f4;
typedef __attribute__((ext_vector_type(8))) short short8v;   // 8 bf16
typedef __attribute__((ext_vector_type(4))) float f32x4;
typedef unsigned short u16;
typedef unsigned int u32;

__device__ __forceinline__ void gll16b(const void* g, void* l) {
  __builtin_amdgcn_global_load_lds(
      (const __attribute__((address_space(1))) void*)g,
      (__attribute__((address_space(3))) void*)l, 16, 0, 0);
}

__device__ __forceinline__ u16 f2bf(float f) {  // RNE f32->bf16
  u32 u = __float_as_uint(f);
  return (u16)((u + 0x7FFFu + ((u >> 16) & 1u)) >> 16);
}

// ======== K1/K2: C = [relu](Amat @ Bmat[KTOT][256]) ========
// 256 thr; block 32 rows x 256 cols; thread 8 rows x 4 cols; BK=16.
// A: LDS [32][16] dbuf (2KB), read as wave-uniform b128 bcast.
// B: LDS [16][256] dbuf (16KB), read as stride-1 b128 (conflict-free).
template <int KTOT, bool RELU>
__global__ __launch_bounds__(256) void k_tile(const float* __restrict__ Amat, int lda,
                                              const float* __restrict__ Bmat,
                                              float* __restrict__ Cout) {
  __shared__ float As[2][32 * 16];   // 4 KB total
  __shared__ float Bs[2][16 * 256];  // 32 KB total
  const int i0 = blockIdx.x * 32;
  const int tid = threadIdx.x;
  const int rg = tid >> 6;   // 0..3, wave-uniform
  const int ct = tid & 63;   // cols ct*4..+3
  const int r0 = rg * 8;
  constexpr int NC = KTOT / 16;
  float acc[8][4] = {};

  // stage chunk 0
  if (tid < 128)
    gll16b(&Amat[(size_t)(i0 + (tid >> 2)) * lda + (tid & 3) * 4], &As[0][tid * 4]);
#pragma unroll
  for (int w = 0; w < 4; ++w) {
    const int lin = tid + 256 * w;
    gll16b(&Bmat[(size_t)(lin >> 6) * DE + (lin & 63) * 4], &Bs[0][lin * 4]);
  }

  for (int c = 0; c < NC; ++c) {
    __syncthreads();  // drains stage of chunk c; prior compute done
    if (c + 1 < NC) {
      const int kb = (c + 1) * 16;
      if (tid < 128)
        gll16b(&Amat[(size_t)(i0 + (tid >> 2)) * lda + kb + (tid & 3) * 4],
               &As[(c + 1) & 1][tid * 4]);
#pragma unroll
      for (int w = 0; w < 4; ++w) {
        const int lin = tid + 256 * w;
        gll16b(&Bmat[(size_t)(kb + (lin >> 6)) * DE + (lin & 63) * 4],
               &Bs[(c + 1) & 1][lin * 4]);
      }
    }
    const float* as = &As[c & 1][0];
    const float* bs = &Bs[c & 1][0];
#pragma unroll
    for (int k4 = 0; k4 < 4; ++k4) {
      f4 a[8];
#pragma unroll
      for (int u = 0; u < 8; ++u)
        a[u] = *(const f4*)&as[(r0 + u) * 16 + k4 * 4];  // uniform bcast
#pragma unroll
      for (int kk = 0; kk < 4; ++kk) {  // global k = c*16+k4*4+kk ascending
        f4 b = *(const f4*)&bs[(k4 * 4 + kk) * 256 + ct * 4];  // b128 stride-1
        const float* bf = (const float*)&b;
#pragma unroll
        for (int u = 0; u < 8; ++u) {
          const float av = ((const float*)&a[u])[kk];
#pragma unroll
          for (int m = 0; m < 4; ++m)
            acc[u][m] = __fmaf_rn(av, bf[m], acc[u][m]);
        }
      }
    }
  }
#pragma unroll
  for (int u = 0; u < 8; ++u) {
    f4 o;
    float* of = (float*)&o;
#pragma unroll
    for (int m = 0; m < 4; ++m) of[m] = RELU ? fmaxf(acc[u][m], 0.0f) : acc[u][m];
    *(f4*)&Cout[(size_t)(i0 + r0 + u) * DE + ct * 4] = o;
  }
}

// ======== K3: sq (numpy-pairwise, exact) + hbbC bf16 chunked layout ========
__global__ __launch_bounds__(256) void k_sq32(const float* __restrict__ hb,
                                              float* __restrict__ sq,
                                              u16* __restrict__ hbbC) {
  const int row = blockIdx.x * 256 + threadIdx.x;
  const float* h = hb + (size_t)row * DE;
  float half[2];
#pragma unroll
  for (int hx = 0; hx < 2; ++hx) {
    float p[8] = {};
    for (int t = 0; t < 16; ++t) {
      const int k0 = hx * 128 + t * 8;
      f4 v0 = *(const f4*)&h[k0];
      f4 v1 = *(const f4*)&h[k0 + 4];
      const float* v0f = (const float*)&v0;
      const float* v1f = (const float*)&v1;
      short8v pk;
#pragma unroll
      for (int m = 0; m < 4; ++m) {
        p[m] = __fadd_rn(p[m], __fmul_rn(v0f[m], v0f[m]));
        p[4 + m] = __fadd_rn(p[4 + m], __fmul_rn(v1f[m], v1f[m]));
        pk[m] = (short)f2bf(v0f[m]);
        pk[4 + m] = (short)f2bf(v1f[m]);
      }
      *(short8v*)&hbbC[((size_t)(k0 >> 5) * NN + row) * 32 + (k0 & 31)] = pk;
    }
    const float t01 = __fadd_rn(p[0], p[1]), t23 = __fadd_rn(p[2], p[3]);
    const float t45 = __fadd_rn(p[4], p[5]), t67 = __fadd_rn(p[6], p[7]);
    half[hx] = __fadd_rn(__fadd_rn(t01, t23), __fadd_rn(t45, t67));
  }
  sq[row] = __fadd_rn(half[0], half[1]);
}

// ======== K4: bf16 MFMA screening + per-selector top-16 lists ========
__global__ __launch_bounds__(512) void k_scr(const u16* __restrict__ hbbC,
                                             const float* __restrict__ sqv,
                                             const float* __restrict__ q,
                                             const float* __restrict__ temp,
                                             float* __restrict__ wsV,
                                             int* __restrict__ wsJ) {
  __shared__ u16 Asb[8192];      // [8 kc][32 row][32 k] bf16, 16 KB
  __shared__ u16 Bsb[2][8192];   // [256 j][32 k] bf16 dbuf, 32 KB
  __shared__ float ssc[8192];    // [32 row][256 col] f32, 32 KB
  const int i0 = blockIdx.x * 32;
  const int tid = threadIdx.x;
  const int wv = tid >> 6;
  const int l = tid & 63;
  const int l4 = l >> 4, ll = l & 15;
  const int sr = tid >> 4, ss = tid & 15;

#pragma unroll
  for (int w2 = 0; w2 < 2; ++w2) {
    const int lin = tid + 512 * w2;
    gll16b(hbbC + ((size_t)(lin >> 7) * NN + i0) * 32 + (lin & 127) * 8,
           Asb + (size_t)lin * 8);
    gll16b(hbbC + (size_t)lin * 8, Bsb[0] + (size_t)lin * 8);
  }
  __syncthreads();

  short8v Areg[8][2];
#pragma unroll
  for (int kc = 0; kc < 8; ++kc)
#pragma unroll
    for (int rf = 0; rf < 2; ++rf)
      Areg[kc][rf] = *(const short8v*)&Asb[kc * 1024 + (rf * 16 + ll) * 32 + l4 * 8];

  const float tt = fminf(fmaxf(temp[0], -5.0f), 5.0f);
  const float C = expf(tt);
  float sqi[2][4];
#pragma unroll
  for (int rf = 0; rf < 2; ++rf)
#pragma unroll
    for (int r = 0; r < 4; ++r) sqi[rf][r] = sqv[i0 + rf * 16 + l4 * 4 + r];

  f32x4 acc[2][2] = {{{0.f, 0.f, 0.f, 0.f}, {0.f, 0.f, 0.f, 0.f}},
                     {{0.f, 0.f, 0.f, 0.f}, {0.f, 0.f, 0.f, 0.f}}};
  float lv[16];
  int lj[16];
#pragma unroll
  for (int u = 0; u < TK; ++u) { lv[u] = -3.0e38f; lj[u] = 0x7fffffff; }

  for (int cc = 0; cc < 256; ++cc) {  // jt = cc>>3, kc = cc&7
    __syncthreads();
    if (cc + 1 < 256) {
      const int jt1 = (cc + 1) >> 3, kc1 = (cc + 1) & 7;
#pragma unroll
      for (int w2 = 0; w2 < 2; ++w2) {
        const int lin = tid + 512 * w2;
        gll16b(hbbC + (size_t)kc1 * (NN * 32) + (size_t)jt1 * 8192 + (size_t)lin * 8,
               Bsb[(cc + 1) & 1] + (size_t)lin * 8);
      }
    }
    const int kc = cc & 7;
    const u16* bs = Bsb[cc & 1];
#pragma unroll
    for (int cf = 0; cf < 2; ++cf) {
      short8v bfr = *(const short8v*)&bs[(wv * 32 + cf * 16 + ll) * 32 + l4 * 8];
#pragma unroll
      for (int rf = 0; rf < 2; ++rf)
        acc[rf][cf] = __builtin_amdgcn_mfma_f32_16x16x32_bf16(
            Areg[kc][rf], bfr, acc[rf][cf], 0, 0, 0);
    }
    if ((cc & 7) == 7) {
      const int jt = cc >> 3;
#pragma unroll
      for (int rf = 0; rf < 2; ++rf)
#pragma unroll
        for (int cf = 0; cf < 2; ++cf) {
          const int col = wv * 32 + cf * 16 + ll;
          const int j = jt * 256 + col;
          const float sqj = sqv[j];
#pragma unroll
          for (int r = 0; r < 4; ++r) {
            const int row = rf * 16 + l4 * 4 + r;
            float D = sqi[rf][r] + sqj - 2.0f * acc[rf][cf][r];
            D = fmaxf(D, 0.0f);
            const float qv = q[(size_t)(i0 + row) * NN + j];
            ssc[row * 256 + col] = logf(-logf(qv + 1e-8f)) - C * D;
            acc[rf][cf][r] = 0.0f;
          }
        }
      __syncthreads();
      for (int c2 = 0; c2 < 16; ++c2) {
        const float v = ssc[sr * 256 + c2 * 16 + ss];
        if (v > lv[15]) {
          float cv = v;
          int cj = jt * 256 + c2 * 16 + ss;
#pragma unroll
          for (int u = 0; u < TK; ++u) {
            const bool take = (cv > lv[u]);
            const float nv2 = take ? cv : lv[u];
            const int nj2 = take ? cj : lj[u];
            cv = take ? lv[u] : cv;
            cj = take ? lj[u] : cj;
            lv[u] = nv2;
            lj[u] = nj2;
          }
        }
      }
    }
  }

  const size_t base = ((size_t)(i0 + sr) * 16 + ss) * (size_t)TK;
#pragma unroll
  for (int u = 0; u < TK; ++u) {
    wsV[base + u] = lv[u];
    wsJ[base + u] = lj[u];
  }
}

// ======== K5: per-row screen-t16 threshold -> compact candidate list ========
__global__ __launch_bounds__(64) void k_thr(const float* __restrict__ wsV,
                                            const int* __restrict__ wsJ,
                                            int* __restrict__ wsC,
                                            int* __restrict__ wsN) {
  const int r = blockIdx.x * 64 + threadIdx.x;
  const float* V = wsV + (size_t)r * 256;
  const int* J = wsJ + (size_t)r * 256;
  int cur[16];
#pragma unroll
  for (int u = 0; u < 16; ++u) cur[u] = 0;
  float t16 = -3.0e38f;
  for (int it = 0; it < TK; ++it) {
    float bv = -3.0e38f;
    int bj = 0x7fffffff, bl = 0;
    for (int u = 0; u < 16; ++u) {
      const int c = cur[u];
      if (c < TK) {
        const float v = V[u * TK + c];
        const int j = J[u * TK + c];
        if (v > bv || (v == bv && j < bj)) { bv = v; bj = j; bl = u; }
      }
    }
    cur[bl]++;
    t16 = bv;
  }
  const float tau = t16 - 0.02f;  // 10x the bf16 screen-error bound
  int cnt = 0;
  int* myc = wsC + (size_t)r * 32;
  for (int ci = 0; ci < 256; ++ci)
    if (V[ci] >= tau && cnt < 32) myc[cnt++] = J[ci];
  wsN[r] = cnt;
}

// ======== K6: exact canonical-f32 re-score of candidates ========
__global__ __launch_bounds__(256) void k_rfn(const int* __restrict__ wsC,
                                             const int* __restrict__ wsN,
                                             const float* __restrict__ hb,
                                             const float* __restrict__ sqv,
                                             const float* __restrict__ q,
                                             const float* __restrict__ temp,
                                             float* __restrict__ wsE) {
  const int gid = blockIdx.x * 256 + threadIdx.x;
  const int r = gid >> 5;
  const int slot = gid & 31;
  float s = -3.0e38f;
  if (slot < wsN[r]) {
    const int j = wsC[(size_t)r * 32 + slot];
    const float* hi = hb + (size_t)r * DE;
    const float* hj = hb + (size_t)j * DE;
    float d = 0.0f;
    for (int k4 = 0; k4 < 64; ++k4) {  // k ascending, canonical FMA chain
      f4 a = *(const f4*)&hi[k4 * 4];
      f4 b = *(const f4*)&hj[k4 * 4];
      d = __fmaf_rn(a.x, b.x, d);
      d = __fmaf_rn(a.y, b.y, d);
      d = __fmaf_rn(a.z, b.z, d);
      d = __fmaf_rn(a.w, b.w, d);
    }
    const float tt = fminf(fmaxf(temp[0], -5.0f), 5.0f);
    const float C = expf(tt);
    const float t1 = __fadd_rn(sqv[r], sqv[j]);
    float D = __fsub_rn(t1, __fmul_rn(2.0f, d));
    D = fmaxf(D, 0.0f);
    const float lg = __fmul_rn(D, C);
    const float p = __fadd_rn(q[(size_t)r * NN + j], 1e-8f);
    const float uu = logf(p);
    const float nv = logf(-uu);
    s = __fsub_rn(nv, lg);
  }
  wsE[(size_t)r * 32 + slot] = s;
}

// ======== K7: exact top-16 (value desc, index asc) per row ========
__global__ __launch_bounds__(64) void k_fin(const float* __restrict__ wsE,
                                            const int* __restrict__ wsC,
                                            const int* __restrict__ wsN,
                                            float* __restrict__ out) {
  const int r = blockIdx.x * 64 + threadIdx.x;
  const int cnt = wsN[r];
  float lv[16];
  int lj[16];
#pragma unroll
  for (int u = 0; u < TK; ++u) { lv[u] = -3.0e38f; lj[u] = 0x7fffffff; }
  for (int ci = 0; ci < cnt; ++ci) {
    const float v = wsE[(size_t)r * 32 + ci];
    const int j = wsC[(size_t)r * 32 + ci];
    if (v > lv[15] || (v == lv[15] && j < lj[15])) {
      float cv = v;
      int cj = j;
#pragma unroll
      for (int u = 0; u < TK; ++u) {
        const bool take = (cv > lv[u]) || (cv == lv[u] && cj < lj[u]);
        const float nv2 = take ? cv : lv[u];
        const int nj2 = take ? cj : lj[u];
        cv = take ? lv[u] : cv;
        cj = take ? lj[u] : cj;
        lv[u] = nv2;
        lj[u] = nj2;
      }
    }
  }
  float* E0 = out + (size_t)NN * DE;
  float* E1 = E0 + (size_t)NN * TK;
  float* LP = E1 + (size_t)NN * TK;
#pragma unroll
  for (int u = 0; u < TK; ++u) {
    E0[(size_t)r * TK + u] = (float)lj[u];
    E1[(size_t)r * TK + u] = (float)r;
    LP[(size_t)r * TK + u] = lv[u];
  }
}

extern "C" void kernel_launch(void* const* d_in, const int* in_sizes, int n_in,
                              void* d_out, int out_size, void* d_ws, size_t ws_size,
                              hipStream_t stream) {
  const float* x = (const float*)d_in[0];
  const float* A = (const float*)d_in[1];
  const float* W = (const float*)d_in[2];
  const float* temp = (const float*)d_in[3];
  const float* q = (const float*)d_in[4];
  float* out = (float*)d_out;

  char* ws = (char*)d_ws;
  float* xw   = (float*)(ws);             //  8,388,608 B
  float* sq   = (float*)(ws + 8388608);   //     32,768 B
  u16*   hbbC = (u16*)  (ws + 8421376);   //  4,194,304 B  [8][8192][32] bf16
  float* wsV  = (float*)(ws + 12615680);  //  8,388,608 B  [8192][16][16]
  int*   wsJ  = (int*)  (ws + 21004288);  //  8,388,608 B
  int*   wsC  = (int*)  (ws + 29392896);  //  1,048,576 B  [8192][32]
  int*   wsN  = (int*)  (ws + 30441472);  //     32,768 B
  float* wsE  = (float*)(ws + 30474240);  //  1,048,576 B  [8192][32]

  float* hb = out;  // [N, DE] f32 output region holds h

  hipLaunchKernelGGL((k_tile<DI, false>), dim3(NN / 32), dim3(256), 0, stream, x, DI, W, xw);
  hipLaunchKernelGGL((k_tile<NN, true>), dim3(NN / 32), dim3(256), 0, stream, A, NN, xw, hb);
  hipLaunchKernelGGL(k_sq32, dim3(NN / 256), dim3(256), 0, stream, hb, sq, hbbC);
  hipLaunchKernelGGL(k_scr, dim3(NN / 32), dim3(512), 0, stream, hbbC, sq, q, temp, wsV, wsJ);
  hipLaunchKernelGGL(k_thr, dim3(NN / 64), dim3(64), 0, stream, wsV, wsJ, wsC, wsN);
  hipLaunchKernelGGL(k_rfn, dim3(NN * 32 / 256), dim3(256), 0, stream, wsC, wsN, hb, sq, q, temp, wsE);
  hipLaunchKernelGGL(k_fin, dim3(NN / 64), dim3(64), 0, stream, wsE, wsC, wsN, out);
}

// Round 14
// 1601.260 us; speedup vs baseline: 1.0559x; 1.0559x over previous
//
#include <hip/hip_runtime.h>
#include <math.h>

// DGM edge sampler, N=8192, DIN=512, DEMB=256, K=16.
// Canonical-f32 pipeline for h and all REFINED scores (bit-faithful to the
// np reference). bf16 MFMA screening + exact f32 refine for the O(N^2) part.
// Round 14: k_tile -> 16x256 tile, 256 thr, grid 512 (2 blocks/CU -> 8 waves
// from two INDEPENDENT blocks; round-13's grid=256 capped every variant at
// 1 block/CU). BK=16, R8C2, A wave-uniform broadcast, B b64 stride-1.
// k-order unchanged (0..KTOT-1 ascending) -> bit-identical h.

#define NN 8192
#define DI 512
#define DE 256
#define TK 16

typedef float4 f4;
typedef __attribute__((ext_vector_type(8))) short short8v;   // 8 bf16
typedef __attribute__((ext_vector_type(4))) float f32x4;
typedef unsigned short u16;
typedef unsigned int u32;

__device__ __forceinline__ void gll16b(const void* g, void* l) {
  __builtin_amdgcn_global_load_lds(
      (const __attribute__((address_space(1))) void*)g,
      (__attribute__((address_space(3))) void*)l, 16, 0, 0);
}

__device__ __forceinline__ u16 f2bf(float f) {  // RNE f32->bf16
  u32 u = __float_as_uint(f);
  return (u16)((u + 0x7FFFu + ((u >> 16) & 1u)) >> 16);
}

// ======== K1/K2: C = [relu](Amat @ Bmat[KTOT][256]) ========
// 256 thr; block 16 rows x 256 cols; thread 8 rows x 2 cols; BK=16; grid 512.
// A: LDS [16][16] dbuf (2KB), read as wave-uniform b128 bcast (rg=tid>>7).
// B: LDS [16][256] dbuf (32KB), read as stride-1 b64 (2-way, free).
template <int KTOT, bool RELU>
__global__ __launch_bounds__(256) void k_tile(const float* __restrict__ Amat, int lda,
                                              const float* __restrict__ Bmat,
                                              float* __restrict__ Cout) {
  __shared__ float As[2][16 * 16];   // 2 KB total
  __shared__ float Bs[2][16 * 256];  // 32 KB total
  const int i0 = blockIdx.x * 16;
  const int tid = threadIdx.x;
  const int rg = tid >> 7;   // 0..1, wave-uniform (waves 0,1 -> 0; waves 2,3 -> 1)
  const int ct = tid & 127;  // cols ct*2, ct*2+1
  const int r0 = rg * 8;
  constexpr int NC = KTOT / 16;
  float acc[8][2] = {};

  // stage chunk 0
  if (tid < 64)
    gll16b(&Amat[(size_t)(i0 + (tid >> 2)) * lda + (tid & 3) * 4], &As[0][tid * 4]);
#pragma unroll
  for (int w = 0; w < 4; ++w) {
    const int lin = tid + 256 * w;
    gll16b(&Bmat[(size_t)(lin >> 6) * DE + (lin & 63) * 4], &Bs[0][lin * 4]);
  }

  for (int c = 0; c < NC; ++c) {
    __syncthreads();  // drains stage of chunk c; prior compute done
    if (c + 1 < NC) {
      const int kb = (c + 1) * 16;
      if (tid < 64)
        gll16b(&Amat[(size_t)(i0 + (tid >> 2)) * lda + kb + (tid & 3) * 4],
               &As[(c + 1) & 1][tid * 4]);
#pragma unroll
      for (int w = 0; w < 4; ++w) {
        const int lin = tid + 256 * w;
        gll16b(&Bmat[(size_t)(kb + (lin >> 6)) * DE + (lin & 63) * 4],
               &Bs[(c + 1) & 1][lin * 4]);
      }
    }
    const float* as = &As[c & 1][0];
    const float* bs = &Bs[c & 1][0];
#pragma unroll
    for (int k4 = 0; k4 < 4; ++k4) {
      f4 a[8];
#pragma unroll
      for (int u = 0; u < 8; ++u)
        a[u] = *(const f4*)&as[(r0 + u) * 16 + k4 * 4];  // uniform bcast
#pragma unroll
      for (int kk = 0; kk < 4; ++kk) {  // global k = c*16+k4*4+kk ascending
        float2 b = *(const float2*)&bs[(k4 * 4 + kk) * 256 + ct * 2];
#pragma unroll
        for (int u = 0; u < 8; ++u) {
          const float av = ((const float*)&a[u])[kk];
          acc[u][0] = __fmaf_rn(av, b.x, acc[u][0]);
          acc[u][1] = __fmaf_rn(av, b.y, acc[u][1]);
        }
      }
    }
  }
#pragma unroll
  for (int u = 0; u < 8; ++u) {
    float2 o;
    o.x = RELU ? fmaxf(acc[u][0], 0.0f) : acc[u][0];
    o.y = RELU ? fmaxf(acc[u][1], 0.0f) : acc[u][1];
    *(float2*)&Cout[(size_t)(i0 + r0 + u) * DE + ct * 2] = o;
  }
}

// ======== K3: sq (numpy-pairwise, exact) + hbbC bf16 chunked layout ========
__global__ __launch_bounds__(256) void k_sq32(const float* __restrict__ hb,
                                              float* __restrict__ sq,
                                              u16* __restrict__ hbbC) {
  const int row = blockIdx.x * 256 + threadIdx.x;
  const float* h = hb + (size_t)row * DE;
  float half[2];
#pragma unroll
  for (int hx = 0; hx < 2; ++hx) {
    float p[8] = {};
    for (int t = 0; t < 16; ++t) {
      const int k0 = hx * 128 + t * 8;
      f4 v0 = *(const f4*)&h[k0];
      f4 v1 = *(const f4*)&h[k0 + 4];
      const float* v0f = (const float*)&v0;
      const float* v1f = (const float*)&v1;
      short8v pk;
#pragma unroll
      for (int m = 0; m < 4; ++m) {
        p[m] = __fadd_rn(p[m], __fmul_rn(v0f[m], v0f[m]));
        p[4 + m] = __fadd_rn(p[4 + m], __fmul_rn(v1f[m], v1f[m]));
        pk[m] = (short)f2bf(v0f[m]);
        pk[4 + m] = (short)f2bf(v1f[m]);
      }
      *(short8v*)&hbbC[((size_t)(k0 >> 5) * NN + row) * 32 + (k0 & 31)] = pk;
    }
    const float t01 = __fadd_rn(p[0], p[1]), t23 = __fadd_rn(p[2], p[3]);
    const float t45 = __fadd_rn(p[4], p[5]), t67 = __fadd_rn(p[6], p[7]);
    half[hx] = __fadd_rn(__fadd_rn(t01, t23), __fadd_rn(t45, t67));
  }
  sq[row] = __fadd_rn(half[0], half[1]);
}

// ======== K4: bf16 MFMA screening + per-selector top-16 lists ========
__global__ __launch_bounds__(512) void k_scr(const u16* __restrict__ hbbC,
                                             const float* __restrict__ sqv,
                                             const float* __restrict__ q,
                                             const float* __restrict__ temp,
                                             float* __restrict__ wsV,
                                             int* __restrict__ wsJ) {
  __shared__ u16 Asb[8192];      // [8 kc][32 row][32 k] bf16, 16 KB
  __shared__ u16 Bsb[2][8192];   // [256 j][32 k] bf16 dbuf, 32 KB
  __shared__ float ssc[8192];    // [32 row][256 col] f32, 32 KB
  const int i0 = blockIdx.x * 32;
  const int tid = threadIdx.x;
  const int wv = tid >> 6;
  const int l = tid & 63;
  const int l4 = l >> 4, ll = l & 15;
  const int sr = tid >> 4, ss = tid & 15;

#pragma unroll
  for (int w2 = 0; w2 < 2; ++w2) {
    const int lin = tid + 512 * w2;
    gll16b(hbbC + ((size_t)(lin >> 7) * NN + i0) * 32 + (lin & 127) * 8,
           Asb + (size_t)lin * 8);
    gll16b(hbbC + (size_t)lin * 8, Bsb[0] + (size_t)lin * 8);
  }
  __syncthreads();

  short8v Areg[8][2];
#pragma unroll
  for (int kc = 0; kc < 8; ++kc)
#pragma unroll
    for (int rf = 0; rf < 2; ++rf)
      Areg[kc][rf] = *(const short8v*)&Asb[kc * 1024 + (rf * 16 + ll) * 32 + l4 * 8];

  const float tt = fminf(fmaxf(temp[0], -5.0f), 5.0f);
  const float C = expf(tt);
  float sqi[2][4];
#pragma unroll
  for (int rf = 0; rf < 2; ++rf)
#pragma unroll
    for (int r = 0; r < 4; ++r) sqi[rf][r] = sqv[i0 + rf * 16 + l4 * 4 + r];

  f32x4 acc[2][2] = {{{0.f, 0.f, 0.f, 0.f}, {0.f, 0.f, 0.f, 0.f}},
                     {{0.f, 0.f, 0.f, 0.f}, {0.f, 0.f, 0.f, 0.f}}};
  float lv[16];
  int lj[16];
#pragma unroll
  for (int u = 0; u < TK; ++u) { lv[u] = -3.0e38f; lj[u] = 0x7fffffff; }

  for (int cc = 0; cc < 256; ++cc) {  // jt = cc>>3, kc = cc&7
    __syncthreads();
    if (cc + 1 < 256) {
      const int jt1 = (cc + 1) >> 3, kc1 = (cc + 1) & 7;
#pragma unroll
      for (int w2 = 0; w2 < 2; ++w2) {
        const int lin = tid + 512 * w2;
        gll16b(hbbC + (size_t)kc1 * (NN * 32) + (size_t)jt1 * 8192 + (size_t)lin * 8,
               Bsb[(cc + 1) & 1] + (size_t)lin * 8);
      }
    }
    const int kc = cc & 7;
    const u16* bs = Bsb[cc & 1];
#pragma unroll
    for (int cf = 0; cf < 2; ++cf) {
      short8v bfr = *(const short8v*)&bs[(wv * 32 + cf * 16 + ll) * 32 + l4 * 8];
#pragma unroll
      for (int rf = 0; rf < 2; ++rf)
        acc[rf][cf] = __builtin_amdgcn_mfma_f32_16x16x32_bf16(
            Areg[kc][rf], bfr, acc[rf][cf], 0, 0, 0);
    }
    if ((cc & 7) == 7) {
      const int jt = cc >> 3;
#pragma unroll
      for (int rf = 0; rf < 2; ++rf)
#pragma unroll
        for (int cf = 0; cf < 2; ++cf) {
          const int col = wv * 32 + cf * 16 + ll;
          const int j = jt * 256 + col;
          const float sqj = sqv[j];
#pragma unroll
          for (int r = 0; r < 4; ++r) {
            const int row = rf * 16 + l4 * 4 + r;
            float D = sqi[rf][r] + sqj - 2.0f * acc[rf][cf][r];
            D = fmaxf(D, 0.0f);
            const float qv = q[(size_t)(i0 + row) * NN + j];
            ssc[row * 256 + col] = logf(-logf(qv + 1e-8f)) - C * D;
            acc[rf][cf][r] = 0.0f;
          }
        }
      __syncthreads();
      for (int c2 = 0; c2 < 16; ++c2) {
        const float v = ssc[sr * 256 + c2 * 16 + ss];
        if (v > lv[15]) {
          float cv = v;
          int cj = jt * 256 + c2 * 16 + ss;
#pragma unroll
          for (int u = 0; u < TK; ++u) {
            const bool take = (cv > lv[u]);
            const float nv2 = take ? cv : lv[u];
            const int nj2 = take ? cj : lj[u];
            cv = take ? lv[u] : cv;
            cj = take ? lj[u] : cj;
            lv[u] = nv2;
            lj[u] = nj2;
          }
        }
      }
    }
  }

  const size_t base = ((size_t)(i0 + sr) * 16 + ss) * (size_t)TK;
#pragma unroll
  for (int u = 0; u < TK; ++u) {
    wsV[base + u] = lv[u];
    wsJ[base + u] = lj[u];
  }
}

// ======== K5: per-row screen-t16 threshold -> compact candidate list ========
__global__ __launch_bounds__(64) void k_thr(const float* __restrict__ wsV,
                                            const int* __restrict__ wsJ,
                                            int* __restrict__ wsC,
                                            int* __restrict__ wsN) {
  const int r = blockIdx.x * 64 + threadIdx.x;
  const float* V = wsV + (size_t)r * 256;
  const int* J = wsJ + (size_t)r * 256;
  int cur[16];
#pragma unroll
  for (int u = 0; u < 16; ++u) cur[u] = 0;
  float t16 = -3.0e38f;
  for (int it = 0; it < TK; ++it) {
    float bv = -3.0e38f;
    int bj = 0x7fffffff, bl = 0;
    for (int u = 0; u < 16; ++u) {
      const int c = cur[u];
      if (c < TK) {
        const float v = V[u * TK + c];
        const int j = J[u * TK + c];
        if (v > bv || (v == bv && j < bj)) { bv = v; bj = j; bl = u; }
      }
    }
    cur[bl]++;
    t16 = bv;
  }
  const float tau = t16 - 0.02f;  // 10x the bf16 screen-error bound
  int cnt = 0;
  int* myc = wsC + (size_t)r * 32;
  for (int ci = 0; ci < 256; ++ci)
    if (V[ci] >= tau && cnt < 32) myc[cnt++] = J[ci];
  wsN[r] = cnt;
}

// ======== K6: exact canonical-f32 re-score of candidates ========
__global__ __launch_bounds__(256) void k_rfn(const int* __restrict__ wsC,
                                             const int* __restrict__ wsN,
                                             const float* __restrict__ hb,
                                             const float* __restrict__ sqv,
                                             const float* __restrict__ q,
                                             const float* __restrict__ temp,
                                             float* __restrict__ wsE) {
  const int gid = blockIdx.x * 256 + threadIdx.x;
  const int r = gid >> 5;
  const int slot = gid & 31;
  float s = -3.0e38f;
  if (slot < wsN[r]) {
    const int j = wsC[(size_t)r * 32 + slot];
    const float* hi = hb + (size_t)r * DE;
    const float* hj = hb + (size_t)j * DE;
    float d = 0.0f;
    for (int k4 = 0; k4 < 64; ++k4) {  // k ascending, canonical FMA chain
      f4 a = *(const f4*)&hi[k4 * 4];
      f4 b = *(const f4*)&hj[k4 * 4];
      d = __fmaf_rn(a.x, b.x, d);
      d = __fmaf_rn(a.y, b.y, d);
      d = __fmaf_rn(a.z, b.z, d);
      d = __fmaf_rn(a.w, b.w, d);
    }
    const float tt = fminf(fmaxf(temp[0], -5.0f), 5.0f);
    const float C = expf(tt);
    const float t1 = __fadd_rn(sqv[r], sqv[j]);
    float D = __fsub_rn(t1, __fmul_rn(2.0f, d));
    D = fmaxf(D, 0.0f);
    const float lg = __fmul_rn(D, C);
    const float p = __fadd_rn(q[(size_t)r * NN + j], 1e-8f);
    const float uu = logf(p);
    const float nv = logf(-uu);
    s = __fsub_rn(nv, lg);
  }
  wsE[(size_t)r * 32 + slot] = s;
}

// ======== K7: exact top-16 (value desc, index asc) per row ========
__global__ __launch_bounds__(64) void k_fin(const float* __restrict__ wsE,
                                            const int* __restrict__ wsC,
                                            const int* __restrict__ wsN,
                                            float* __restrict__ out) {
  const int r = blockIdx.x * 64 + threadIdx.x;
  const int cnt = wsN[r];
  float lv[16];
  int lj[16];
#pragma unroll
  for (int u = 0; u < TK; ++u) { lv[u] = -3.0e38f; lj[u] = 0x7fffffff; }
  for (int ci = 0; ci < cnt; ++ci) {
    const float v = wsE[(size_t)r * 32 + ci];
    const int j = wsC[(size_t)r * 32 + ci];
    if (v > lv[15] || (v == lv[15] && j < lj[15])) {
      float cv = v;
      int cj = j;
#pragma unroll
      for (int u = 0; u < TK; ++u) {
        const bool take = (cv > lv[u]) || (cv == lv[u] && cj < lj[u]);
        const float nv2 = take ? cv : lv[u];
        const int nj2 = take ? cj : lj[u];
        cv = take ? lv[u] : cv;
        cj = take ? lj[u] : cj;
        lv[u] = nv2;
        lj[u] = nj2;
      }
    }
  }
  float* E0 = out + (size_t)NN * DE;
  float* E1 = E0 + (size_t)NN * TK;
  float* LP = E1 + (size_t)NN * TK;
#pragma unroll
  for (int u = 0; u < TK; ++u) {
    E0[(size_t)r * TK + u] = (float)lj[u];
    E1[(size_t)r * TK + u] = (float)r;
    LP[(size_t)r * TK + u] = lv[u];
  }
}

extern "C" void kernel_launch(void* const* d_in, const int* in_sizes, int n_in,
                              void* d_out, int out_size, void* d_ws, size_t ws_size,
                              hipStream_t stream) {
  const float* x = (const float*)d_in[0];
  const float* A = (const float*)d_in[1];
  const float* W = (const float*)d_in[2];
  const float* temp = (const float*)d_in[3];
  const float* q = (const float*)d_in[4];
  float* out = (float*)d_out;

  char* ws = (char*)d_ws;
  float* xw   = (float*)(ws);             //  8,388,608 B
  float* sq   = (float*)(ws + 8388608);   //     32,768 B
  u16*   hbbC = (u16*)  (ws + 8421376);   //  4,194,304 B  [8][8192][32] bf16
  float* wsV  = (float*)(ws + 12615680);  //  8,388,608 B  [8192][16][16]
  int*   wsJ  = (int*)  (ws + 21004288);  //  8,388,608 B
  int*   wsC  = (int*)  (ws + 29392896);  //  1,048,576 B  [8192][32]
  int*   wsN  = (int*)  (ws + 30441472);  //     32,768 B
  float* wsE  = (float*)(ws + 30474240);  //  1,048,576 B  [8192][32]

  float* hb = out;  // [N, DE] f32 output region holds h

  hipLaunchKernelGGL((k_tile<DI, false>), dim3(NN / 16), dim3(256), 0, stream, x, DI, W, xw);
  hipLaunchKernelGGL((k_tile<NN, true>), dim3(NN / 16), dim3(256), 0, stream, A, NN, xw, hb);
  hipLaunchKernelGGL(k_sq32, dim3(NN / 256), dim3(256), 0, stream, hb, sq, hbbC);
  hipLaunchKernelGGL(k_scr, dim3(NN / 32), dim3(512), 0, stream, hbbC, sq, q, temp, wsV, wsJ);
  hipLaunchKernelGGL(k_thr, dim3(NN / 64), dim3(64), 0, stream, wsV, wsJ, wsC, wsN);
  hipLaunchKernelGGL(k_rfn, dim3(NN * 32 / 256), dim3(256), 0, stream, wsC, wsN, hb, sq, q, temp, wsE);
  hipLaunchKernelGGL(k_fin, dim3(NN / 64), dim3(64), 0, stream, wsE, wsC, wsN, out);
}

// Round 15
// 1530.658 us; speedup vs baseline: 1.1046x; 1.0461x over previous
//
#include <hip/hip_runtime.h>
#include <math.h>

// DGM edge sampler, N=8192, DIN=512, DEMB=256, K=16.
// Canonical-f32 pipeline for h and all REFINED scores (bit-faithful to the
// np reference). bf16 MFMA screening + exact f32 refine for the O(N^2) part.
// Round 15: k_tile thread-tile 8x2 -> 4x4, all-b128 LDS reads (32 instr vs 48
// per thread/chunk). Discriminates LDS-instruction-rate model (predicts
// ~560us) vs byte-rate model (predicts no change) for the k_tile wall.
// k-order unchanged (0..KTOT-1 ascending) -> bit-identical h.

#define NN 8192
#define DI 512
#define DE 256
#define TK 16

typedef float4 f4;
typedef __attribute__((ext_vector_type(8))) short short8v;   // 8 bf16
typedef __attribute__((ext_vector_type(4))) float f32x4;
typedef unsigned short u16;
typedef unsigned int u32;

__device__ __forceinline__ void gll16b(const void* g, void* l) {
  __builtin_amdgcn_global_load_lds(
      (const __attribute__((address_space(1))) void*)g,
      (__attribute__((address_space(3))) void*)l, 16, 0, 0);
}

__device__ __forceinline__ u16 f2bf(float f) {  // RNE f32->bf16
  u32 u = __float_as_uint(f);
  return (u16)((u + 0x7FFFu + ((u >> 16) & 1u)) >> 16);
}

// ======== K1/K2: C = [relu](Amat @ Bmat[KTOT][256]) ========
// 256 thr; block 16 rows x 256 cols; thread 4 rows x 4 cols; BK=16; grid 512.
// A: LDS [16][16] dbuf, read as wave-uniform b128 bcast (rg=tid>>6, 16 instr).
// B: LDS [16][256] dbuf, read as stride-1 b128 (16 instr).
template <int KTOT, bool RELU>
__global__ __launch_bounds__(256) void k_tile(const float* __restrict__ Amat, int lda,
                                              const float* __restrict__ Bmat,
                                              float* __restrict__ Cout) {
  __shared__ float As[2][16 * 16];   // 2 KB total
  __shared__ float Bs[2][16 * 256];  // 32 KB total
  const int i0 = blockIdx.x * 16;
  const int tid = threadIdx.x;
  const int rg = tid >> 6;   // 0..3, wave-uniform
  const int cg = tid & 63;   // cols cg*4..+3
  const int r0 = rg * 4;
  constexpr int NC = KTOT / 16;
  float acc[4][4] = {};

  // stage chunk 0
  if (tid < 64)
    gll16b(&Amat[(size_t)(i0 + (tid >> 2)) * lda + (tid & 3) * 4], &As[0][tid * 4]);
#pragma unroll
  for (int w = 0; w < 4; ++w) {
    const int lin = tid + 256 * w;
    gll16b(&Bmat[(size_t)(lin >> 6) * DE + (lin & 63) * 4], &Bs[0][lin * 4]);
  }

  for (int c = 0; c < NC; ++c) {
    __syncthreads();  // drains stage of chunk c; prior compute done
    if (c + 1 < NC) {
      const int kb = (c + 1) * 16;
      if (tid < 64)
        gll16b(&Amat[(size_t)(i0 + (tid >> 2)) * lda + kb + (tid & 3) * 4],
               &As[(c + 1) & 1][tid * 4]);
#pragma unroll
      for (int w = 0; w < 4; ++w) {
        const int lin = tid + 256 * w;
        gll16b(&Bmat[(size_t)(kb + (lin >> 6)) * DE + (lin & 63) * 4],
               &Bs[(c + 1) & 1][lin * 4]);
      }
    }
    const float* as = &As[c & 1][0];
    const float* bs = &Bs[c & 1][0];
#pragma unroll
    for (int k4 = 0; k4 < 4; ++k4) {
      f4 a[4];
#pragma unroll
      for (int u = 0; u < 4; ++u)
        a[u] = *(const f4*)&as[(r0 + u) * 16 + k4 * 4];  // uniform bcast b128
#pragma unroll
      for (int kk = 0; kk < 4; ++kk) {  // global k = c*16+k4*4+kk ascending
        f4 b = *(const f4*)&bs[(k4 * 4 + kk) * 256 + cg * 4];  // stride-1 b128
        const float* bf = (const float*)&b;
#pragma unroll
        for (int u = 0; u < 4; ++u) {
          const float av = ((const float*)&a[u])[kk];
#pragma unroll
          for (int m = 0; m < 4; ++m)
            acc[u][m] = __fmaf_rn(av, bf[m], acc[u][m]);
        }
      }
    }
  }
#pragma unroll
  for (int u = 0; u < 4; ++u) {
    f4 o;
    float* of = (float*)&o;
#pragma unroll
    for (int m = 0; m < 4; ++m) of[m] = RELU ? fmaxf(acc[u][m], 0.0f) : acc[u][m];
    *(f4*)&Cout[(size_t)(i0 + r0 + u) * DE + cg * 4] = o;
  }
}

// ======== K3: sq (numpy-pairwise, exact) + hbbC bf16 chunked layout ========
__global__ __launch_bounds__(256) void k_sq32(const float* __restrict__ hb,
                                              float* __restrict__ sq,
                                              u16* __restrict__ hbbC) {
  const int row = blockIdx.x * 256 + threadIdx.x;
  const float* h = hb + (size_t)row * DE;
  float half[2];
#pragma unroll
  for (int hx = 0; hx < 2; ++hx) {
    float p[8] = {};
    for (int t = 0; t < 16; ++t) {
      const int k0 = hx * 128 + t * 8;
      f4 v0 = *(const f4*)&h[k0];
      f4 v1 = *(const f4*)&h[k0 + 4];
      const float* v0f = (const float*)&v0;
      const float* v1f = (const float*)&v1;
      short8v pk;
#pragma unroll
      for (int m = 0; m < 4; ++m) {
        p[m] = __fadd_rn(p[m], __fmul_rn(v0f[m], v0f[m]));
        p[4 + m] = __fadd_rn(p[4 + m], __fmul_rn(v1f[m], v1f[m]));
        pk[m] = (short)f2bf(v0f[m]);
        pk[4 + m] = (short)f2bf(v1f[m]);
      }
      *(short8v*)&hbbC[((size_t)(k0 >> 5) * NN + row) * 32 + (k0 & 31)] = pk;
    }
    const float t01 = __fadd_rn(p[0], p[1]), t23 = __fadd_rn(p[2], p[3]);
    const float t45 = __fadd_rn(p[4], p[5]), t67 = __fadd_rn(p[6], p[7]);
    half[hx] = __fadd_rn(__fadd_rn(t01, t23), __fadd_rn(t45, t67));
  }
  sq[row] = __fadd_rn(half[0], half[1]);
}

// ======== K4: bf16 MFMA screening + per-selector top-16 lists ========
__global__ __launch_bounds__(512) void k_scr(const u16* __restrict__ hbbC,
                                             const float* __restrict__ sqv,
                                             const float* __restrict__ q,
                                             const float* __restrict__ temp,
                                             float* __restrict__ wsV,
                                             int* __restrict__ wsJ) {
  __shared__ u16 Asb[8192];      // [8 kc][32 row][32 k] bf16, 16 KB
  __shared__ u16 Bsb[2][8192];   // [256 j][32 k] bf16 dbuf, 32 KB
  __shared__ float ssc[8192];    // [32 row][256 col] f32, 32 KB
  const int i0 = blockIdx.x * 32;
  const int tid = threadIdx.x;
  const int wv = tid >> 6;
  const int l = tid & 63;
  const int l4 = l >> 4, ll = l & 15;
  const int sr = tid >> 4, ss = tid & 15;

#pragma unroll
  for (int w2 = 0; w2 < 2; ++w2) {
    const int lin = tid + 512 * w2;
    gll16b(hbbC + ((size_t)(lin >> 7) * NN + i0) * 32 + (lin & 127) * 8,
           Asb + (size_t)lin * 8);
    gll16b(hbbC + (size_t)lin * 8, Bsb[0] + (size_t)lin * 8);
  }
  __syncthreads();

  short8v Areg[8][2];
#pragma unroll
  for (int kc = 0; kc < 8; ++kc)
#pragma unroll
    for (int rf = 0; rf < 2; ++rf)
      Areg[kc][rf] = *(const short8v*)&Asb[kc * 1024 + (rf * 16 + ll) * 32 + l4 * 8];

  const float tt = fminf(fmaxf(temp[0], -5.0f), 5.0f);
  const float C = expf(tt);
  float sqi[2][4];
#pragma unroll
  for (int rf = 0; rf < 2; ++rf)
#pragma unroll
    for (int r = 0; r < 4; ++r) sqi[rf][r] = sqv[i0 + rf * 16 + l4 * 4 + r];

  f32x4 acc[2][2] = {{{0.f, 0.f, 0.f, 0.f}, {0.f, 0.f, 0.f, 0.f}},
                     {{0.f, 0.f, 0.f, 0.f}, {0.f, 0.f, 0.f, 0.f}}};
  float lv[16];
  int lj[16];
#pragma unroll
  for (int u = 0; u < TK; ++u) { lv[u] = -3.0e38f; lj[u] = 0x7fffffff; }

  for (int cc = 0; cc < 256; ++cc) {  // jt = cc>>3, kc = cc&7
    __syncthreads();
    if (cc + 1 < 256) {
      const int jt1 = (cc + 1) >> 3, kc1 = (cc + 1) & 7;
#pragma unroll
      for (int w2 = 0; w2 < 2; ++w2) {
        const int lin = tid + 512 * w2;
        gll16b(hbbC + (size_t)kc1 * (NN * 32) + (size_t)jt1 * 8192 + (size_t)lin * 8,
               Bsb[(cc + 1) & 1] + (size_t)lin * 8);
      }
    }
    const int kc = cc & 7;
    const u16* bs = Bsb[cc & 1];
#pragma unroll
    for (int cf = 0; cf < 2; ++cf) {
      short8v bfr = *(const short8v*)&bs[(wv * 32 + cf * 16 + ll) * 32 + l4 * 8];
#pragma unroll
      for (int rf = 0; rf < 2; ++rf)
        acc[rf][cf] = __builtin_amdgcn_mfma_f32_16x16x32_bf16(
            Areg[kc][rf], bfr, acc[rf][cf], 0, 0, 0);
    }
    if ((cc & 7) == 7) {
      const int jt = cc >> 3;
#pragma unroll
      for (int rf = 0; rf < 2; ++rf)
#pragma unroll
        for (int cf = 0; cf < 2; ++cf) {
          const int col = wv * 32 + cf * 16 + ll;
          const int j = jt * 256 + col;
          const float sqj = sqv[j];
#pragma unroll
          for (int r = 0; r < 4; ++r) {
            const int row = rf * 16 + l4 * 4 + r;
            float D = sqi[rf][r] + sqj - 2.0f * acc[rf][cf][r];
            D = fmaxf(D, 0.0f);
            const float qv = q[(size_t)(i0 + row) * NN + j];
            ssc[row * 256 + col] = logf(-logf(qv + 1e-8f)) - C * D;
            acc[rf][cf][r] = 0.0f;
          }
        }
      __syncthreads();
      for (int c2 = 0; c2 < 16; ++c2) {
        const float v = ssc[sr * 256 + c2 * 16 + ss];
        if (v > lv[15]) {
          float cv = v;
          int cj = jt * 256 + c2 * 16 + ss;
#pragma unroll
          for (int u = 0; u < TK; ++u) {
            const bool take = (cv > lv[u]);
            const float nv2 = take ? cv : lv[u];
            const int nj2 = take ? cj : lj[u];
            cv = take ? lv[u] : cv;
            cj = take ? lj[u] : cj;
            lv[u] = nv2;
            lj[u] = nj2;
          }
        }
      }
    }
  }

  const size_t base = ((size_t)(i0 + sr) * 16 + ss) * (size_t)TK;
#pragma unroll
  for (int u = 0; u < TK; ++u) {
    wsV[base + u] = lv[u];
    wsJ[base + u] = lj[u];
  }
}

// ======== K5: per-row screen-t16 threshold -> compact candidate list ========
__global__ __launch_bounds__(64) void k_thr(const float* __restrict__ wsV,
                                            const int* __restrict__ wsJ,
                                            int* __restrict__ wsC,
                                            int* __restrict__ wsN) {
  const int r = blockIdx.x * 64 + threadIdx.x;
  const float* V = wsV + (size_t)r * 256;
  const int* J = wsJ + (size_t)r * 256;
  int cur[16];
#pragma unroll
  for (int u = 0; u < 16; ++u) cur[u] = 0;
  float t16 = -3.0e38f;
  for (int it = 0; it < TK; ++it) {
    float bv = -3.0e38f;
    int bj = 0x7fffffff, bl = 0;
    for (int u = 0; u < 16; ++u) {
      const int c = cur[u];
      if (c < TK) {
        const float v = V[u * TK + c];
        const int j = J[u * TK + c];
        if (v > bv || (v == bv && j < bj)) { bv = v; bj = j; bl = u; }
      }
    }
    cur[bl]++;
    t16 = bv;
  }
  const float tau = t16 - 0.02f;  // 10x the bf16 screen-error bound
  int cnt = 0;
  int* myc = wsC + (size_t)r * 32;
  for (int ci = 0; ci < 256; ++ci)
    if (V[ci] >= tau && cnt < 32) myc[cnt++] = J[ci];
  wsN[r] = cnt;
}

// ======== K6: exact canonical-f32 re-score of candidates ========
__global__ __launch_bounds__(256) void k_rfn(const int* __restrict__ wsC,
                                             const int* __restrict__ wsN,
                                             const float* __restrict__ hb,
                                             const float* __restrict__ sqv,
                                             const float* __restrict__ q,
                                             const float* __restrict__ temp,
                                             float* __restrict__ wsE) {
  const int gid = blockIdx.x * 256 + threadIdx.x;
  const int r = gid >> 5;
  const int slot = gid & 31;
  float s = -3.0e38f;
  if (slot < wsN[r]) {
    const int j = wsC[(size_t)r * 32 + slot];
    const float* hi = hb + (size_t)r * DE;
    const float* hj = hb + (size_t)j * DE;
    float d = 0.0f;
    for (int k4 = 0; k4 < 64; ++k4) {  // k ascending, canonical FMA chain
      f4 a = *(const f4*)&hi[k4 * 4];
      f4 b = *(const f4*)&hj[k4 * 4];
      d = __fmaf_rn(a.x, b.x, d);
      d = __fmaf_rn(a.y, b.y, d);
      d = __fmaf_rn(a.z, b.z, d);
      d = __fmaf_rn(a.w, b.w, d);
    }
    const float tt = fminf(fmaxf(temp[0], -5.0f), 5.0f);
    const float C = expf(tt);
    const float t1 = __fadd_rn(sqv[r], sqv[j]);
    float D = __fsub_rn(t1, __fmul_rn(2.0f, d));
    D = fmaxf(D, 0.0f);
    const float lg = __fmul_rn(D, C);
    const float p = __fadd_rn(q[(size_t)r * NN + j], 1e-8f);
    const float uu = logf(p);
    const float nv = logf(-uu);
    s = __fsub_rn(nv, lg);
  }
  wsE[(size_t)r * 32 + slot] = s;
}

// ======== K7: exact top-16 (value desc, index asc) per row ========
__global__ __launch_bounds__(64) void k_fin(const float* __restrict__ wsE,
                                            const int* __restrict__ wsC,
                                            const int* __restrict__ wsN,
                                            float* __restrict__ out) {
  const int r = blockIdx.x * 64 + threadIdx.x;
  const int cnt = wsN[r];
  float lv[16];
  int lj[16];
#pragma unroll
  for (int u = 0; u < TK; ++u) { lv[u] = -3.0e38f; lj[u] = 0x7fffffff; }
  for (int ci = 0; ci < cnt; ++ci) {
    const float v = wsE[(size_t)r * 32 + ci];
    const int j = wsC[(size_t)r * 32 + ci];
    if (v > lv[15] || (v == lv[15] && j < lj[15])) {
      float cv = v;
      int cj = j;
#pragma unroll
      for (int u = 0; u < TK; ++u) {
        const bool take = (cv > lv[u]) || (cv == lv[u] && cj < lj[u]);
        const float nv2 = take ? cv : lv[u];
        const int nj2 = take ? cj : lj[u];
        cv = take ? lv[u] : cv;
        cj = take ? lj[u] : cj;
        lv[u] = nv2;
        lj[u] = nj2;
      }
    }
  }
  float* E0 = out + (size_t)NN * DE;
  float* E1 = E0 + (size_t)NN * TK;
  float* LP = E1 + (size_t)NN * TK;
#pragma unroll
  for (int u = 0; u < TK; ++u) {
    E0[(size_t)r * TK + u] = (float)lj[u];
    E1[(size_t)r * TK + u] = (float)r;
    LP[(size_t)r * TK + u] = lv[u];
  }
}

extern "C" void kernel_launch(void* const* d_in, const int* in_sizes, int n_in,
                              void* d_out, int out_size, void* d_ws, size_t ws_size,
                              hipStream_t stream) {
  const float* x = (const float*)d_in[0];
  const float* A = (const float*)d_in[1];
  const float* W = (const float*)d_in[2];
  const float* temp = (const float*)d_in[3];
  const float* q = (const float*)d_in[4];
  float* out = (float*)d_out;

  char* ws = (char*)d_ws;
  float* xw   = (float*)(ws);             //  8,388,608 B
  float* sq   = (float*)(ws + 8388608);   //     32,768 B
  u16*   hbbC = (u16*)  (ws + 8421376);   //  4,194,304 B  [8][8192][32] bf16
  float* wsV  = (float*)(ws + 12615680);  //  8,388,608 B  [8192][16][16]
  int*   wsJ  = (int*)  (ws + 21004288);  //  8,388,608 B
  int*   wsC  = (int*)  (ws + 29392896);  //  1,048,576 B  [8192][32]
  int*   wsN  = (int*)  (ws + 30441472);  //     32,768 B
  float* wsE  = (float*)(ws + 30474240);  //  1,048,576 B  [8192][32]

  float* hb = out;  // [N, DE] f32 output region holds h

  hipLaunchKernelGGL((k_tile<DI, false>), dim3(NN / 16), dim3(256), 0, stream, x, DI, W, xw);
  hipLaunchKernelGGL((k_tile<NN, true>), dim3(NN / 16), dim3(256), 0, stream, A, NN, xw, hb);
  hipLaunchKernelGGL(k_sq32, dim3(NN / 256), dim3(256), 0, stream, hb, sq, hbbC);
  hipLaunchKernelGGL(k_scr, dim3(NN / 32), dim3(512), 0, stream, hbbC, sq, q, temp, wsV, wsJ);
  hipLaunchKernelGGL(k_thr, dim3(NN / 64), dim3(64), 0, stream, wsV, wsJ, wsC, wsN);
  hipLaunchKernelGGL(k_rfn, dim3(NN * 32 / 256), dim3(256), 0, stream, wsC, wsN, hb, sq, q, temp, wsE);
  hipLaunchKernelGGL(k_fin, dim3(NN / 64), dim3(64), 0, stream, wsE, wsC, wsN, out);
}

// Round 17
// 1350.375 us; speedup vs baseline: 1.2520x; 1.1335x over previous
//
#include <hip/hip_runtime.h>
#include <math.h>

// DGM edge sampler, N=8192, DIN=512, DEMB=256, K=16.
// Canonical-f32 pipeline for h and all REFINED scores (bit-faithful to the
// np reference). bf16 MFMA screening + exact f32 refine for the O(N^2) part.
// Round 17: revert to the r15-passing source (r16's 4-way k_scr rewrite
// failed); single change: k_scr's chunk loop becomes jt x unrolled-kc so
// Areg[kc] is compile-time-indexed (rule #20: runtime-indexed ext_vector
// arrays go to scratch -> ~1GB of scratch traffic eliminated). Memory ops,
// barriers, MFMA order all identical -> bit-identical outputs.

#define NN 8192
#define DI 512
#define DE 256
#define TK 16

typedef float4 f4;
typedef __attribute__((ext_vector_type(8))) short short8v;   // 8 bf16
typedef __attribute__((ext_vector_type(4))) float f32x4;
typedef unsigned short u16;
typedef unsigned int u32;

__device__ __forceinline__ void gll16b(const void* g, void* l) {
  __builtin_amdgcn_global_load_lds(
      (const __attribute__((address_space(1))) void*)g,
      (__attribute__((address_space(3))) void*)l, 16, 0, 0);
}

__device__ __forceinline__ u16 f2bf(float f) {  // RNE f32->bf16
  u32 u = __float_as_uint(f);
  return (u16)((u + 0x7FFFu + ((u >> 16) & 1u)) >> 16);
}

// ======== K1/K2: C = [relu](Amat @ Bmat[KTOT][256])  (r15 proven) ========
template <int KTOT, bool RELU>
__global__ __launch_bounds__(256) void k_tile(const float* __restrict__ Amat, int lda,
                                              const float* __restrict__ Bmat,
                                              float* __restrict__ Cout) {
  __shared__ float As[2][16 * 16];   // 2 KB total
  __shared__ float Bs[2][16 * 256];  // 32 KB total
  const int i0 = blockIdx.x * 16;
  const int tid = threadIdx.x;
  const int rg = tid >> 6;   // 0..3, wave-uniform
  const int cg = tid & 63;   // cols cg*4..+3
  const int r0 = rg * 4;
  constexpr int NC = KTOT / 16;
  float acc[4][4] = {};

  if (tid < 64)
    gll16b(&Amat[(size_t)(i0 + (tid >> 2)) * lda + (tid & 3) * 4], &As[0][tid * 4]);
#pragma unroll
  for (int w = 0; w < 4; ++w) {
    const int lin = tid + 256 * w;
    gll16b(&Bmat[(size_t)(lin >> 6) * DE + (lin & 63) * 4], &Bs[0][lin * 4]);
  }

  for (int c = 0; c < NC; ++c) {
    __syncthreads();
    if (c + 1 < NC) {
      const int kb = (c + 1) * 16;
      if (tid < 64)
        gll16b(&Amat[(size_t)(i0 + (tid >> 2)) * lda + kb + (tid & 3) * 4],
               &As[(c + 1) & 1][tid * 4]);
#pragma unroll
      for (int w = 0; w < 4; ++w) {
        const int lin = tid + 256 * w;
        gll16b(&Bmat[(size_t)(kb + (lin >> 6)) * DE + (lin & 63) * 4],
               &Bs[(c + 1) & 1][lin * 4]);
      }
    }
    const float* as = &As[c & 1][0];
    const float* bs = &Bs[c & 1][0];
#pragma unroll
    for (int k4 = 0; k4 < 4; ++k4) {
      f4 a[4];
#pragma unroll
      for (int u = 0; u < 4; ++u)
        a[u] = *(const f4*)&as[(r0 + u) * 16 + k4 * 4];  // uniform bcast b128
#pragma unroll
      for (int kk = 0; kk < 4; ++kk) {  // global k ascending
        f4 b = *(const f4*)&bs[(k4 * 4 + kk) * 256 + cg * 4];  // stride-1 b128
        const float* bf = (const float*)&b;
#pragma unroll
        for (int u = 0; u < 4; ++u) {
          const float av = ((const float*)&a[u])[kk];
#pragma unroll
          for (int m = 0; m < 4; ++m)
            acc[u][m] = __fmaf_rn(av, bf[m], acc[u][m]);
        }
      }
    }
  }
#pragma unroll
  for (int u = 0; u < 4; ++u) {
    f4 o;
    float* of = (float*)&o;
#pragma unroll
    for (int m = 0; m < 4; ++m) of[m] = RELU ? fmaxf(acc[u][m], 0.0f) : acc[u][m];
    *(f4*)&Cout[(size_t)(i0 + r0 + u) * DE + cg * 4] = o;
  }
}

// ======== K3: sq (numpy-pairwise, exact) + hbbC bf16 chunked layout ========
__global__ __launch_bounds__(256) void k_sq32(const float* __restrict__ hb,
                                              float* __restrict__ sq,
                                              u16* __restrict__ hbbC) {
  const int row = blockIdx.x * 256 + threadIdx.x;
  const float* h = hb + (size_t)row * DE;
  float half2x[2];
#pragma unroll
  for (int hx = 0; hx < 2; ++hx) {
    float p[8] = {};
    for (int t = 0; t < 16; ++t) {
      const int k0 = hx * 128 + t * 8;
      f4 v0 = *(const f4*)&h[k0];
      f4 v1 = *(const f4*)&h[k0 + 4];
      const float* v0f = (const float*)&v0;
      const float* v1f = (const float*)&v1;
      short8v pk;
#pragma unroll
      for (int m = 0; m < 4; ++m) {
        p[m] = __fadd_rn(p[m], __fmul_rn(v0f[m], v0f[m]));
        p[4 + m] = __fadd_rn(p[4 + m], __fmul_rn(v1f[m], v1f[m]));
        pk[m] = (short)f2bf(v0f[m]);
        pk[4 + m] = (short)f2bf(v1f[m]);
      }
      *(short8v*)&hbbC[((size_t)(k0 >> 5) * NN + row) * 32 + (k0 & 31)] = pk;
    }
    const float t01 = __fadd_rn(p[0], p[1]), t23 = __fadd_rn(p[2], p[3]);
    const float t45 = __fadd_rn(p[4], p[5]), t67 = __fadd_rn(p[6], p[7]);
    half2x[hx] = __fadd_rn(__fadd_rn(t01, t23), __fadd_rn(t45, t67));
  }
  sq[row] = __fadd_rn(half2x[0], half2x[1]);
}

// ======== K4: bf16 MFMA screening + per-selector top-16 lists ========
// r12/r15-proven structure; ONLY change: jt x unrolled-kc loop so Areg[kc]
// is compile-time-indexed (register-resident, no scratch).
__global__ __launch_bounds__(512) void k_scr(const u16* __restrict__ hbbC,
                                             const float* __restrict__ sqv,
                                             const float* __restrict__ q,
                                             const float* __restrict__ temp,
                                             float* __restrict__ wsV,
                                             int* __restrict__ wsJ) {
  __shared__ u16 Asb[8192];      // [8 kc][32 row][32 k] bf16, 16 KB
  __shared__ u16 Bsb[2][8192];   // [256 j][32 k] bf16 dbuf, 32 KB
  __shared__ float ssc[8192];    // [32 row][256 col] f32, 32 KB
  const int i0 = blockIdx.x * 32;
  const int tid = threadIdx.x;
  const int wv = tid >> 6;
  const int l = tid & 63;
  const int l4 = l >> 4, ll = l & 15;
  const int sr = tid >> 4, ss = tid & 15;

#pragma unroll
  for (int w2 = 0; w2 < 2; ++w2) {
    const int lin = tid + 512 * w2;
    gll16b(hbbC + ((size_t)(lin >> 7) * NN + i0) * 32 + (lin & 127) * 8,
           Asb + (size_t)lin * 8);
    gll16b(hbbC + (size_t)lin * 8, Bsb[0] + (size_t)lin * 8);
  }
  __syncthreads();

  short8v Areg[8][2];
#pragma unroll
  for (int kc = 0; kc < 8; ++kc)
#pragma unroll
    for (int rf = 0; rf < 2; ++rf)
      Areg[kc][rf] = *(const short8v*)&Asb[kc * 1024 + (rf * 16 + ll) * 32 + l4 * 8];

  const float tt = fminf(fmaxf(temp[0], -5.0f), 5.0f);
  const float C = expf(tt);
  float sqi[2][4];
#pragma unroll
  for (int rf = 0; rf < 2; ++rf)
#pragma unroll
    for (int r = 0; r < 4; ++r) sqi[rf][r] = sqv[i0 + rf * 16 + l4 * 4 + r];

  f32x4 acc[2][2] = {{{0.f, 0.f, 0.f, 0.f}, {0.f, 0.f, 0.f, 0.f}},
                     {{0.f, 0.f, 0.f, 0.f}, {0.f, 0.f, 0.f, 0.f}}};
  float lv[16];
  int lj[16];
#pragma unroll
  for (int u = 0; u < TK; ++u) { lv[u] = -3.0e38f; lj[u] = 0x7fffffff; }

  for (int jt = 0; jt < 32; ++jt) {
#pragma unroll
    for (int kc = 0; kc < 8; ++kc) {   // compile-time kc; order == flat cc loop
      __syncthreads();
      const int cn = jt * 8 + kc + 1;  // next chunk index (== cc+1)
      if (cn < 256) {
        const int jt1 = cn >> 3, kc1 = cn & 7;
#pragma unroll
        for (int w2 = 0; w2 < 2; ++w2) {
          const int lin = tid + 512 * w2;
          gll16b(hbbC + (size_t)kc1 * (NN * 32) + (size_t)jt1 * 8192 + (size_t)lin * 8,
                 Bsb[cn & 1] + (size_t)lin * 8);
        }
      }
      const u16* bs = Bsb[kc & 1];     // (jt*8+kc)&1 == kc&1
#pragma unroll
      for (int cf = 0; cf < 2; ++cf) {
        short8v bfr = *(const short8v*)&bs[(wv * 32 + cf * 16 + ll) * 32 + l4 * 8];
#pragma unroll
        for (int rf = 0; rf < 2; ++rf)
          acc[rf][cf] = __builtin_amdgcn_mfma_f32_16x16x32_bf16(
              Areg[kc][rf], bfr, acc[rf][cf], 0, 0, 0);
      }
      if (kc == 7) {
#pragma unroll
        for (int rf = 0; rf < 2; ++rf)
#pragma unroll
          for (int cf = 0; cf < 2; ++cf) {
            const int col = wv * 32 + cf * 16 + ll;
            const int j = jt * 256 + col;
            const float sqj = sqv[j];
#pragma unroll
            for (int r = 0; r < 4; ++r) {
              const int row = rf * 16 + l4 * 4 + r;
              float D = sqi[rf][r] + sqj - 2.0f * acc[rf][cf][r];
              D = fmaxf(D, 0.0f);
              const float qv = q[(size_t)(i0 + row) * NN + j];
              ssc[row * 256 + col] = logf(-logf(qv + 1e-8f)) - C * D;
              acc[rf][cf][r] = 0.0f;
            }
          }
        __syncthreads();
        for (int c2 = 0; c2 < 16; ++c2) {
          const float v = ssc[sr * 256 + c2 * 16 + ss];
          if (v > lv[15]) {  // strict: ties keep earlier (smaller) j
            float cv = v;
            int cj = jt * 256 + c2 * 16 + ss;
#pragma unroll
            for (int u = 0; u < TK; ++u) {
              const bool take = (cv > lv[u]);
              const float nv2 = take ? cv : lv[u];
              const int nj2 = take ? cj : lj[u];
              cv = take ? lv[u] : cv;
              cj = take ? lj[u] : cj;
              lv[u] = nv2;
              lj[u] = nj2;
            }
          }
        }
      }
    }
  }

  const size_t base = ((size_t)(i0 + sr) * 16 + ss) * (size_t)TK;
#pragma unroll
  for (int u = 0; u < TK; ++u) {
    wsV[base + u] = lv[u];
    wsJ[base + u] = lj[u];
  }
}

// ======== K5: per-row screen-t16 threshold -> compact candidate list ========
__global__ __launch_bounds__(64) void k_thr(const float* __restrict__ wsV,
                                            const int* __restrict__ wsJ,
                                            int* __restrict__ wsC,
                                            int* __restrict__ wsN) {
  const int r = blockIdx.x * 64 + threadIdx.x;
  const float* V = wsV + (size_t)r * 256;
  const int* J = wsJ + (size_t)r * 256;
  int cur[16];
#pragma unroll
  for (int u = 0; u < 16; ++u) cur[u] = 0;
  float t16 = -3.0e38f;
  for (int it = 0; it < TK; ++it) {
    float bv = -3.0e38f;
    int bj = 0x7fffffff, bl = 0;
    for (int u = 0; u < 16; ++u) {
      const int c = cur[u];
      if (c < TK) {
        const float v = V[u * TK + c];
        const int j = J[u * TK + c];
        if (v > bv || (v == bv && j < bj)) { bv = v; bj = j; bl = u; }
      }
    }
    cur[bl]++;
    t16 = bv;
  }
  const float tau = t16 - 0.02f;  // 10x the bf16 screen-error bound
  int cnt = 0;
  int* myc = wsC + (size_t)r * 32;
  for (int ci = 0; ci < 256; ++ci)
    if (V[ci] >= tau && cnt < 32) myc[cnt++] = J[ci];
  wsN[r] = cnt;
}

// ======== K6: exact canonical-f32 re-score of candidates ========
__global__ __launch_bounds__(256) void k_rfn(const int* __restrict__ wsC,
                                             const int* __restrict__ wsN,
                                             const float* __restrict__ hb,
                                             const float* __restrict__ sqv,
                                             const float* __restrict__ q,
                                             const float* __restrict__ temp,
                                             float* __restrict__ wsE) {
  const int gid = blockIdx.x * 256 + threadIdx.x;
  const int r = gid >> 5;
  const int slot = gid & 31;
  float s = -3.0e38f;
  if (slot < wsN[r]) {
    const int j = wsC[(size_t)r * 32 + slot];
    const float* hi = hb + (size_t)r * DE;
    const float* hj = hb + (size_t)j * DE;
    float d = 0.0f;
    for (int k4 = 0; k4 < 64; ++k4) {  // k ascending, canonical FMA chain
      f4 a = *(const f4*)&hi[k4 * 4];
      f4 b = *(const f4*)&hj[k4 * 4];
      d = __fmaf_rn(a.x, b.x, d);
      d = __fmaf_rn(a.y, b.y, d);
      d = __fmaf_rn(a.z, b.z, d);
      d = __fmaf_rn(a.w, b.w, d);
    }
    const float tt = fminf(fmaxf(temp[0], -5.0f), 5.0f);
    const float C = expf(tt);
    const float t1 = __fadd_rn(sqv[r], sqv[j]);
    float D = __fsub_rn(t1, __fmul_rn(2.0f, d));
    D = fmaxf(D, 0.0f);
    const float lg = __fmul_rn(D, C);
    const float p = __fadd_rn(q[(size_t)r * NN + j], 1e-8f);
    const float uu = logf(p);
    const float nv = logf(-uu);
    s = __fsub_rn(nv, lg);
  }
  wsE[(size_t)r * 32 + slot] = s;
}

// ======== K7: exact top-16 (value desc, index asc) per row ========
__global__ __launch_bounds__(64) void k_fin(const float* __restrict__ wsE,
                                            const int* __restrict__ wsC,
                                            const int* __restrict__ wsN,
                                            float* __restrict__ out) {
  const int r = blockIdx.x * 64 + threadIdx.x;
  const int cnt = wsN[r];
  float lv[16];
  int lj[16];
#pragma unroll
  for (int u = 0; u < TK; ++u) { lv[u] = -3.0e38f; lj[u] = 0x7fffffff; }
  for (int ci = 0; ci < cnt; ++ci) {
    const float v = wsE[(size_t)r * 32 + ci];
    const int j = wsC[(size_t)r * 32 + ci];
    if (v > lv[15] || (v == lv[15] && j < lj[15])) {
      float cv = v;
      int cj = j;
#pragma unroll
      for (int u = 0; u < TK; ++u) {
        const bool take = (cv > lv[u]) || (cv == lv[u] && cj < lj[u]);
        const float nv2 = take ? cv : lv[u];
        const int nj2 = take ? cj : lj[u];
        cv = take ? lv[u] : cv;
        cj = take ? lj[u] : cj;
        lv[u] = nv2;
        lj[u] = nj2;
      }
    }
  }
  float* E0 = out + (size_t)NN * DE;
  float* E1 = E0 + (size_t)NN * TK;
  float* LP = E1 + (size_t)NN * TK;
#pragma unroll
  for (int u = 0; u < TK; ++u) {
    E0[(size_t)r * TK + u] = (float)lj[u];
    E1[(size_t)r * TK + u] = (float)r;
    LP[(size_t)r * TK + u] = lv[u];
  }
}

extern "C" void kernel_launch(void* const* d_in, const int* in_sizes, int n_in,
                              void* d_out, int out_size, void* d_ws, size_t ws_size,
                              hipStream_t stream) {
  const float* x = (const float*)d_in[0];
  const float* A = (const float*)d_in[1];
  const float* W = (const float*)d_in[2];
  const float* temp = (const float*)d_in[3];
  const float* q = (const float*)d_in[4];
  float* out = (float*)d_out;

  char* ws = (char*)d_ws;
  float* xw   = (float*)(ws);             //  8,388,608 B
  float* sq   = (float*)(ws + 8388608);   //     32,768 B
  u16*   hbbC = (u16*)  (ws + 8421376);   //  4,194,304 B  [8][8192][32] bf16
  float* wsV  = (float*)(ws + 12615680);  //  8,388,608 B  [8192][16][16]
  int*   wsJ  = (int*)  (ws + 21004288);  //  8,388,608 B
  int*   wsC  = (int*)  (ws + 29392896);  //  1,048,576 B  [8192][32]
  int*   wsN  = (int*)  (ws + 30441472);  //     32,768 B
  float* wsE  = (float*)(ws + 30474240);  //  1,048,576 B  [8192][32]

  float* hb = out;  // [N, DE] f32 output region holds h

  hipLaunchKernelGGL((k_tile<DI, false>), dim3(NN / 16), dim3(256), 0, stream, x, DI, W, xw);
  hipLaunchKernelGGL((k_tile<NN, true>), dim3(NN / 16), dim3(256), 0, stream, A, NN, xw, hb);
  hipLaunchKernelGGL(k_sq32, dim3(NN / 256), dim3(256), 0, stream, hb, sq, hbbC);
  hipLaunchKernelGGL(k_scr, dim3(NN / 32), dim3(512), 0, stream, hbbC, sq, q, temp, wsV, wsJ);
  hipLaunchKernelGGL(k_thr, dim3(NN / 64), dim3(64), 0, stream, wsV, wsJ, wsC, wsN);
  hipLaunchKernelGGL(k_rfn, dim3(NN * 32 / 256), dim3(256), 0, stream, wsC, wsN, hb, sq, q, temp, wsE);
  hipLaunchKernelGGL(k_fin, dim3(NN / 64), dim3(64), 0, stream, wsE, wsC, wsN, out);
}